// Round 13
// baseline (163.137 us; speedup 1.0000x reference)
//
#include <hip/hip_runtime.h>
#include <math.h>

#define B 16
#define D 8
#define FDIM 2
#define N 512
#define E 10          // D + FDIM
#define NP36 36       // pairs a<=d
#define GJW (2*E)     // augmented width for Gauss-Jordan
#define NT 4          // i-tiles per (pair,b)
#define TIL 128       // i-tile size
#define NQ (NP36*B*NT)        // 2304 k_q blocks
#define NSYS (NP36*B + B*D)   // 576 pair systems + 128 A systems = 704
#define NPREPB (NSYS/4)       // 176 blocks, one wave per system
#define LOG2E 1.44269504088896340736f
#define KA 12         // augmented K (10 + ca + cb), MFMA K padded to 16

// ---- workspace layout (float offsets) ----
#define OFF_MUD  0         // B*D          = 128
#define OFF_V    128       // B*D*E        = 1280
#define OFF_EDDP 1408      // NP36*B*NT    = 2304
#define OFF_TRP  3712      // D*B*NT       = 512
#define OFF_W    4224      // NP36*B*E*E   = 57600
#define OFF_CA   61824     // NP36*B*N     = 294912
#define OFF_CB   356736    // NP36*B*N     = 294912
// total 651648 floats = 2.6 MB

typedef _Float16 f16x4 __attribute__((ext_vector_type(4)));
typedef float f32x4 __attribute__((ext_vector_type(4)));

// raw hardware exp2 (v_exp_f32); CDNA interlocks handle the TRANS latency
__device__ __forceinline__ float exp2_hw(float x) {
  float r;
  __asm__ __volatile__("v_exp_f32 %0, %1" : "=v"(r) : "v"(x));
  return r;
}

__device__ __forceinline__ void decode_pair(int p36, int* pa, int* pd) {
  int a = 0, rem = p36;
  while (rem >= D - a) { rem -= (D - a); a++; }
  *pa = a; *pd = a + rem;
}

__device__ __forceinline__ float wave_reduce(float v) {
#pragma unroll
  for (int off = 32; off > 0; off >>= 1) v += __shfl_down(v, off);
  return v;
}

// compiler fence for wave-synchronous LDS phases (no runtime cost)
__device__ __forceinline__ void wsync() {
  __asm__ __volatile__("" ::: "memory");
  __builtin_amdgcn_wave_barrier();
  __asm__ __volatile__("" ::: "memory");
}

// Wave-synchronous Gauss-Jordan with partial pivoting on E x GJW system in
// LDS. ONE wave, zero block barriers; reads register-cached before writes
// each phase. On exit: M[r][E+c] = left^{-1} * right.
// Returns log|det(left)| (valid in every lane).
__device__ __forceinline__ float gj_wave(float (*M)[GJW], int lane) {
  float pivs[E];
#pragma unroll
  for (int k = 0; k < E; k++) {
    wsync();
    int pr = k;
    float best = fabsf(M[k][k]);
#pragma unroll
    for (int r = 1; r < E; r++) {
      if (r > k) {
        float v = fabsf(M[r][k]);
        if (v > best) { best = v; pr = r; }
      }
    }
    pivs[k] = M[pr][k];
    wsync();
    float tk = 0.f, pw = 0.f;
    if (lane < GJW) {
      float piv = M[pr][k];
      pw = M[pr][lane] / piv;
      tk = M[k][lane];
    }
    wsync();
    if (lane < GJW) {
      M[pr][lane] = tk;
      M[k][lane]  = pw;
    }
    wsync();
    float cf[4], pv[4], cur[4];
    int rr[4], cc[4];
#pragma unroll
    for (int t = 0; t < 4; t++) {
      int idx = lane + t * 64;
      if (idx < E * GJW) {
        int r = idx / GJW, c = idx - r * GJW;
        rr[t] = r; cc[t] = c;
        cf[t]  = M[r][k];
        pv[t]  = M[k][c];
        cur[t] = M[r][c];
      } else {
        rr[t] = k; cc[t] = 0; cf[t] = 0.f; pv[t] = 0.f; cur[t] = 0.f;
      }
    }
    wsync();
#pragma unroll
    for (int t = 0; t < 4; t++) {
      int idx = lane + t * 64;
      if (idx < E * GJW && rr[t] != k) {
        M[rr[t]][cc[t]] = fmaf(-cf[t], pv[t], cur[t]);
      }
    }
  }
  wsync();
  float ld = 0.f;
#pragma unroll
  for (int k = 0; k < E; k++) ld += logf(fabsf(pivs[k]));
  return ld;
}

// ---------------------------------------------------------------------------
// k_prep: ONE WAVE PER SYSTEM, 4 systems/block, no block barriers.
// S/Ainv stay in LDS (broadcast reads) -- NO per-thread matrix arrays
// (R8's register-cached version spilled 100 floats/thread to scratch).
// waves (sid) [0, 576): pair systems -> W (log2e-scaled), CA, CB.
// waves [576, 704): A-path systems -> mu_delta[b,d], V[b,d,:].
__global__ __launch_bounds__(256) void k_prep(
    const float* __restrict__ obs_mean, const float* __restrict__ obs_var,
    const float* __restrict__ action_mean, const float* __restrict__ action_var,
    const float* __restrict__ cross_cov, const float* __restrict__ X,
    const float* __restrict__ ell, const float* __restrict__ alpha_sq,
    const float* __restrict__ beta, float* __restrict__ ws) {
  __shared__ float M[4][E][GJW];
  __shared__ float sSig[4][E * E];
  __shared__ float sMu[4][E], siLa[4][E], siLd[4][E];

  int tid = threadIdx.x;
  int wid = tid >> 6, lane = tid & 63;
  int sid = blockIdx.x * 4 + wid;

  if (sid >= NP36 * B) {
    // ===== A-path wave: mu_delta[b,d], V[b,d,:] =====
    int bd = sid - NP36 * B;
    int b = bd >> 3, d = bd & 7;
    if (lane < E) {
      sMu[wid][lane] = (lane < D) ? obs_mean[b * D + lane]
                                  : action_mean[b * FDIM + lane - D];
    }
    for (int idx = lane; idx < E * E; idx += 64) {
      int e = idx / E, f = idx % E;
      float v;
      if (e < D && f < D)      v = obs_var[(b * D + e) * D + f];
      else if (e < D)          v = cross_cov[(b * D + e) * FDIM + (f - D)];
      else if (f < D)          v = cross_cov[(b * D + f) * FDIM + (e - D)];
      else                     v = action_var[(b * FDIM + (e - D)) * FDIM + (f - D)];
      sSig[wid][idx] = v;
    }
    wsync();
    for (int idx = lane; idx < E * GJW; idx += 64) {
      int r = idx / GJW, c = idx % GJW;
      float v;
      if (c < E) {
        v = sSig[wid][r * E + c];
        if (r == c) { float l = ell[d * E + r]; v += l * l; }
      } else {
        v = (c - E == r) ? 1.0f : 0.0f;
      }
      M[wid][r][c] = v;
    }
    float lda = gj_wave(M[wid], lane);   // M[r][E+c] = Ainv (read from LDS below)
    float a2 = alpha_sq[d];
    float logdetLam = 0.0f;
#pragma unroll
    for (int e = 0; e < E; e++) { float l = ell[d * E + e]; logdetLam += logf(l * l); }
    float c0 = 0.5f * (logdetLam - lda);
    float acc_mu = 0.0f, acc_w[E];
#pragma unroll
    for (int e = 0; e < E; e++) acc_w[e] = 0.0f;
#pragma unroll
    for (int t = 0; t < 8; t++) {
      int n = lane + t * 64;
      float x[E];
#pragma unroll
      for (int e = 0; e < E; e++) x[e] = X[n * E + e] - sMu[wid][e];
      float quad = 0.0f;
#pragma unroll
      for (int e = 0; e < E; e++) {
        float te = 0.0f;
#pragma unroll
        for (int f = 0; f < E; f++) te += M[wid][e][E + f] * x[f];
        quad += x[e] * te;
      }
      float qval = a2 * __expf(c0 - 0.5f * quad);
      float bq = beta[d * N + n] * qval;
      acc_mu += bq;
#pragma unroll
      for (int e = 0; e < E; e++) acc_w[e] += bq * x[e];
    }
    acc_mu = wave_reduce(acc_mu);
#pragma unroll
    for (int e = 0; e < E; e++) acc_w[e] = wave_reduce(acc_w[e]);
    if (lane == 0) {
      ws[OFF_MUD + b * D + d] = acc_mu;
      float u[E];
#pragma unroll
      for (int f = 0; f < E; f++) {
        float s = 0.0f;
#pragma unroll
        for (int g = 0; g < E; g++) s += M[wid][f][E + g] * acc_w[g];
        u[f] = s;
      }
#pragma unroll
      for (int e = 0; e < E; e++) {
        float s = 0.0f;
#pragma unroll
        for (int f = 0; f < E; f++) s += sSig[wid][e * E + f] * u[f];
        ws[OFF_V + (b * D + d) * E + e] = s;
      }
    }
    return;
  }

  // ===== pair wave: W, CA, CB for (p36, b) =====
  int p36 = sid >> 4, b = sid & 15;
  int a, d;
  decode_pair(p36, &a, &d);
  int pb = p36 * B + b;
  if (lane < E) {
    sMu[wid][lane] = (lane < D) ? obs_mean[b * D + lane]
                                : action_mean[b * FDIM + lane - D];
    float la = ell[a * E + lane]; siLa[wid][lane] = 1.0f / (la * la);
    float ld = ell[d * E + lane]; siLd[wid][lane] = 1.0f / (ld * ld);
  }
  for (int idx = lane; idx < E * E; idx += 64) {
    int e = idx / E, f = idx % E;
    float v;
    if (e < D && f < D)      v = obs_var[(b * D + e) * D + f];
    else if (e < D)          v = cross_cov[(b * D + e) * FDIM + (f - D)];
    else if (f < D)          v = cross_cov[(b * D + f) * FDIM + (e - D)];
    else                     v = action_var[(b * FDIM + (e - D)) * FDIM + (f - D)];
    sSig[wid][idx] = v;
  }
  wsync();
  for (int idx = lane; idx < E * GJW; idx += 64) {
    int r = idx / GJW, c = idx % GJW;
    float v;
    if (c < E) v = sSig[wid][r * E + c] * (siLa[wid][c] + siLd[wid][c]) + ((r == c) ? 1.0f : 0.0f);
    else       v = sSig[wid][r * E + (c - E)];
    M[wid][r][c] = v;
  }
  float ldr = gj_wave(M[wid], lane);     // M[r][E+f] = S (read from LDS below)
  float lga = logf(alpha_sq[a]);
  float lgd = logf(alpha_sq[d]);
  for (int idx = lane; idx < E * E; idx += 64) {
    int e = idx / E, f = idx % E;
    ws[OFF_W + pb * (E * E) + idx] = LOG2E * M[wid][e][E + f] * siLa[wid][e] * siLd[wid][f];
  }
#pragma unroll
  for (int t = 0; t < 8; t++) {
    int n = lane + t * 64;
    float pa_[E], pd_[E];
    float s2a = 0.0f, s2b = 0.0f;
#pragma unroll
    for (int e = 0; e < E; e++) {
      float xe = X[n * E + e] - sMu[wid][e];
      pa_[e] = xe * siLa[wid][e];
      pd_[e] = xe * siLd[wid][e];
      s2a += xe * pa_[e];
      s2b += xe * pd_[e];
    }
    float da = 0.0f, db = 0.0f;
#pragma unroll
    for (int e = 0; e < E; e++) {
      float ta = 0.0f, td = 0.0f;
#pragma unroll
      for (int f = 0; f < E; f++) {
        float s = M[wid][e][E + f];
        ta += s * pa_[f];
        td += s * pd_[f];
      }
      da += pa_[e] * ta;
      db += pd_[e] * td;
    }
    ws[OFF_CA + pb * N + n] = LOG2E * (lga - 0.5f * s2a + 0.5f * da - 0.5f * ldr);
    ws[OFF_CB + pb * N + n] = LOG2E * (lgd - 0.5f * s2b + 0.5f * db);
  }
}

// ---------------------------------------------------------------------------
// k_q: Q contraction per (pair, b, i-tile) via split-f16 MFMA.
// A-fragments (T_aug) and sba hoisted into registers (R11-proven).
// This round: TWO j-tiles per loop iteration (j0, j0+16) -- two fully
// independent MFMA->exp->contract chains per iteration give the scheduler
// real ILP by CODE SHAPE. NO launch_bounds override, NO unroll pragma on the
// j-loop: both (256,2) [R12] and unroll-2+(256,2) [R10] miscompiled to NaN.
// Layouts (validated):
//   A frag: row = lane&15, k = 4*(lane>>4)+t   (T_aug rows)
//   B frag: col = lane&15, k = 4*(lane>>4)+t   (nu_aug rows)
//   C/D  : col = lane&15, row = 4*(lane>>4)+r
// K padding: kgrp==3 (k=12..15): B frags forced 0 (predicated); A frags may
// read finite spill (zero-padded array tail) -- product is 0 either way.
__global__ __launch_bounds__(256) void k_q(
    const float* __restrict__ obs_mean, const float* __restrict__ action_mean,
    const float* __restrict__ X, const float* __restrict__ beta,
    const float* __restrict__ invK, float* __restrict__ ws) {
  // stride-12-half rows (24 B): ds_read_b64 banks 6r+2kg mod 32 -> <=2-way (free)
  __shared__ __attribute__((aligned(16))) _Float16 snh[N * KA];        // nu_aug hi
  __shared__ __attribute__((aligned(16))) _Float16 snl[N * KA];        // nu_aug lo
  __shared__ __attribute__((aligned(16))) _Float16 sTh[TIL * KA + 8];  // T_aug hi (+zero pad)
  __shared__ __attribute__((aligned(16))) _Float16 sTl[TIL * KA + 8];  // T_aug lo
  __shared__ float sW[E * E];
  __shared__ float sMu[E];
  __shared__ __attribute__((aligned(16))) float sba[TIL];
  __shared__ float redw[8];

  int tid = threadIdx.x;
  int bx = blockIdx.x;
  int tile = bx & (NT - 1);
  int rest = bx >> 2;
  int b = rest & (B - 1);
  int p36 = rest >> 4;
  int a, d;
  decode_pair(p36, &a, &d);
  int pb = p36 * B + b;
  bool diag = (a == d);
  int i0 = tile * TIL;

  if (tid < E) sMu[tid] = (tid < D) ? obs_mean[b * D + tid] : action_mean[b * FDIM + tid - D];
  if (tid < E * E) sW[tid] = ws[OFF_W + pb * (E * E) + tid];
  if (tid < TIL) sba[tid] = beta[a * N + i0 + tid];
  if (tid < 8) { sTh[TIL * KA + tid] = (_Float16)0.f; sTl[TIL * KA + tid] = (_Float16)0.f; }
  __syncthreads();

  // build nu_aug hi/lo for all 512 j: [nu0..nu9, 1.0, cb_j]
  for (int jj = tid; jj < N; jj += 256) {
    float v[KA];
#pragma unroll
    for (int e = 0; e < E; e++) v[e] = X[jj * E + e] - sMu[e];
    v[10] = 1.0f;
    v[11] = ws[OFF_CB + (size_t)pb * N + jj];
#pragma unroll
    for (int k = 0; k < KA; k++) {
      _Float16 h = (_Float16)v[k];
      snh[jj * KA + k] = h;
      snl[jj * KA + k] = (_Float16)(v[k] - (float)h);
    }
  }

  // build T_aug hi/lo for this i-tile: [t0..t9, ca_i, 1.0]; 2 threads per row
  {
    int il = tid >> 1;
    int k0 = (tid & 1) * 6;
    float nu[E];
#pragma unroll
    for (int e = 0; e < E; e++) nu[e] = X[(i0 + il) * E + e] - sMu[e];
#pragma unroll
    for (int kk = 0; kk < 6; kk++) {
      int k = k0 + kk;
      float v;
      if (k < E) {
        v = 0.f;
#pragma unroll
        for (int e = 0; e < E; e++) v = fmaf(nu[e], sW[e * E + k], v);
      } else if (k == E) {
        v = ws[OFF_CA + (size_t)pb * N + i0 + il];
      } else {
        v = 1.0f;
      }
      _Float16 h = (_Float16)v;
      sTh[il * KA + k] = h;
      sTl[il * KA + k] = (_Float16)(v - (float)h);
    }
  }
  __syncthreads();

  // main loop: 4 waves; each wave covers j-tiles [8w, 8w+8) as 4 pairs
  int lane = tid & 63;
  int w = tid >> 6;
  int c = lane & 15;
  int kg = lane >> 4;
  bool kval = (kg < 3);
  int koff = kg * 4;
  float accRa = 0.f, accRb = 0.f;
  float accT0 = 0.f, accT1 = 0.f, accT2 = 0.f, accT3 = 0.f;
  const float* invKa = invK + (size_t)a * N * N;
  const f32x4 zero4 = {0.f, 0.f, 0.f, 0.f};

  // hoist j-independent state into registers: 16 A-frags + 8 beta_a vectors
  f16x4 Ah[8], Al[8];
  f32x4 bav[8];
#pragma unroll
  for (int it = 0; it < 8; it++) {
    Ah[it] = *(const f16x4*)&sTh[(it * 16 + c) * KA + koff];
    Al[it] = *(const f16x4*)&sTl[(it * 16 + c) * KA + koff];
    bav[it] = *(const f32x4*)&sba[it * 16 + koff];
  }

  for (int jt4 = 0; jt4 < 4; jt4++) {
    int jt0 = (w << 3) + (jt4 << 1);
    int j0 = (jt0 << 4) + c;
    int j1 = j0 + 16;
    f16x4 Bh0 = {(_Float16)0.f, (_Float16)0.f, (_Float16)0.f, (_Float16)0.f};
    f16x4 Bl0 = Bh0, Bh1 = Bh0, Bl1 = Bh0;
    if (kval) {
      Bh0 = *(const f16x4*)&snh[j0 * KA + koff];
      Bl0 = *(const f16x4*)&snl[j0 * KA + koff];
      Bh1 = *(const f16x4*)&snh[j1 * KA + koff];
      Bl1 = *(const f16x4*)&snl[j1 * KA + koff];
    }
    float bd0 = beta[d * N + j0];
    float bd1 = beta[d * N + j1];
    const float* kvrow0 = invKa + (size_t)j0 * N + i0 + koff;
    const float* kvrow1 = invKa + (size_t)j1 * N + i0 + koff;
#pragma unroll
    for (int it = 0; it < 8; it++) {
      // stream 0 (j0) and stream 1 (j1): independent chains
      f32x4 m0 = __builtin_amdgcn_mfma_f32_16x16x16f16(Ah[it], Bh0, zero4, 0, 0, 0);
      f32x4 m1 = __builtin_amdgcn_mfma_f32_16x16x16f16(Ah[it], Bh1, zero4, 0, 0, 0);
      m0 = __builtin_amdgcn_mfma_f32_16x16x16f16(Ah[it], Bl0, m0, 0, 0, 0);
      m1 = __builtin_amdgcn_mfma_f32_16x16x16f16(Ah[it], Bl1, m1, 0, 0, 0);
      m0 = __builtin_amdgcn_mfma_f32_16x16x16f16(Al[it], Bh0, m0, 0, 0, 0);
      m1 = __builtin_amdgcn_mfma_f32_16x16x16f16(Al[it], Bh1, m1, 0, 0, 0);
      float q00 = exp2_hw(m0[0]);
      float q01 = exp2_hw(m0[1]);
      float q02 = exp2_hw(m0[2]);
      float q03 = exp2_hw(m0[3]);
      float q10 = exp2_hw(m1[0]);
      float q11 = exp2_hw(m1[1]);
      float q12 = exp2_hw(m1[2]);
      float q13 = exp2_hw(m1[3]);
      float t0 = bav[it][0] * q00;
      t0 = fmaf(bav[it][1], q01, t0);
      t0 = fmaf(bav[it][2], q02, t0);
      t0 = fmaf(bav[it][3], q03, t0);
      accRa = fmaf(bd0, t0, accRa);
      float t1 = bav[it][0] * q10;
      t1 = fmaf(bav[it][1], q11, t1);
      t1 = fmaf(bav[it][2], q12, t1);
      t1 = fmaf(bav[it][3], q13, t1);
      accRb = fmaf(bd1, t1, accRb);
      if (diag) {
        f32x4 r0 = *(const f32x4*)(kvrow0 + it * 16);
        f32x4 r1 = *(const f32x4*)(kvrow1 + it * 16);
        accT0 = fmaf(r0[0], q00, accT0);
        accT1 = fmaf(r0[1], q01, accT1);
        accT2 = fmaf(r0[2], q02, accT2);
        accT3 = fmaf(r0[3], q03, accT3);
        accT0 = fmaf(r1[0], q10, accT0);
        accT1 = fmaf(r1[1], q11, accT1);
        accT2 = fmaf(r1[2], q12, accT2);
        accT3 = fmaf(r1[3], q13, accT3);
      }
    }
  }

  // reductions (wave shuffle + one LDS step)
  {
    float rr = wave_reduce(accRa + accRb);
    int wid = tid >> 6, ln = tid & 63;
    if (ln == 0) redw[wid] = rr;
    if (diag) {
      float rt = wave_reduce((accT0 + accT1) + (accT2 + accT3));
      if (ln == 0) redw[4 + wid] = rt;
    }
    __syncthreads();
    if (tid == 0) {
      ws[OFF_EDDP + (p36 * B + b) * NT + tile] = redw[0] + redw[1] + redw[2] + redw[3];
      if (diag)
        ws[OFF_TRP + (a * B + b) * NT + tile] = redw[4] + redw[5] + redw[6] + redw[7];
    }
  }
}

// ---------------------------------------------------------------------------
// k_final: assembly (sums tile partials)
__global__ __launch_bounds__(64) void k_final(
    const float* __restrict__ obs_mean, const float* __restrict__ obs_var,
    const float* __restrict__ alpha_sq, const float* __restrict__ sigma_sq_eps,
    const float* __restrict__ ws, float* __restrict__ out) {
  int b = blockIdx.x;
  int tid = threadIdx.x;
  const float* mud = ws + OFF_MUD + b * D;
  if (tid < D) out[b * D + tid] = obs_mean[b * D + tid] + mud[tid];
  if (tid < D * D) {
    int i = tid / D, j = tid % D;
    int a = i < j ? i : j;
    int dd = i < j ? j : i;
    int p36 = a * D - a * (a - 1) / 2 + (dd - a);
    float edd = 0.0f;
#pragma unroll
    for (int tt = 0; tt < NT; tt++) edd += ws[OFF_EDDP + (p36 * B + b) * NT + tt];
    float sd = edd - mud[i] * mud[j];
    if (i == j) {
      float tr = 0.0f;
#pragma unroll
      for (int tt = 0; tt < NT; tt++) tr += ws[OFF_TRP + (i * B + b) * NT + tt];
      sd += alpha_sq[i] - tr + sigma_sq_eps[i];
    }
    const float* V = ws + OFF_V;
    float cxd = V[(b * D + j) * E + i];   // C_xd[b,i,j] = V[b,j,i]
    float cdx = V[(b * D + i) * E + j];   // C_xd[b,j,i] = V[b,i,j]
    out[B * D + b * D * D + tid] = obs_var[b * D * D + tid] + sd + cxd + cdx;
  }
}

// ---------------------------------------------------------------------------
extern "C" void kernel_launch(void* const* d_in, const int* in_sizes, int n_in,
                              void* d_out, int out_size, void* d_ws, size_t ws_size,
                              hipStream_t stream) {
  const float* obs_mean     = (const float*)d_in[0];
  const float* obs_var      = (const float*)d_in[1];
  const float* action_mean  = (const float*)d_in[2];
  const float* action_var   = (const float*)d_in[3];
  const float* cross_cov    = (const float*)d_in[4];
  const float* X_train      = (const float*)d_in[5];
  const float* ell          = (const float*)d_in[6];
  const float* alpha_sq     = (const float*)d_in[7];
  const float* sigma_sq_eps = (const float*)d_in[8];
  const float* beta         = (const float*)d_in[9];
  const float* inv_K        = (const float*)d_in[10];
  float* out = (float*)d_out;
  float* ws = (float*)d_ws;

  k_prep<<<NPREPB, 256, 0, stream>>>(obs_mean, obs_var, action_mean, action_var,
                                     cross_cov, X_train, ell, alpha_sq, beta, ws);
  k_q<<<NQ, 256, 0, stream>>>(obs_mean, action_mean, X_train, beta, inv_K, ws);
  k_final<<<B, 64, 0, stream>>>(obs_mean, obs_var, alpha_sq, sigma_sq_eps, ws, out);
}

// Round 14
// 141.167 us; speedup vs baseline: 1.1556x; 1.1556x over previous
//
#include <hip/hip_runtime.h>
#include <math.h>

#define B 16
#define D 8
#define FDIM 2
#define N 512
#define E 10          // D + FDIM
#define NP36 36       // pairs a<=d
#define GJW (2*E)     // augmented width for Gauss-Jordan
#define NT 4          // i-tiles per (pair,b)
#define TIL 128       // i-tile size
#define NQ (NP36*B*NT)        // 2304 k_q blocks
#define NSYS (NP36*B + B*D)   // 576 pair systems + 128 A systems = 704
#define NPREPB (NSYS/4)       // 176 blocks, one wave per system
#define LOG2E 1.44269504088896340736f
#define KA 12         // augmented K (10 + ca + cb), MFMA K padded to 16
// upper-triangle index for e<=f (55 elements for E=10)
#define TRI(e, f) ((e) * E - (e) * ((e) - 1) / 2 + ((f) - (e)))

// ---- workspace layout (float offsets) ----
#define OFF_MUD  0         // B*D          = 128
#define OFF_V    128       // B*D*E        = 1280
#define OFF_EDDP 1408      // NP36*B*NT    = 2304
#define OFF_TRP  3712      // D*B*NT       = 512
#define OFF_W    4224      // NP36*B*E*E   = 57600
#define OFF_CA   61824     // NP36*B*N     = 294912
#define OFF_CB   356736    // NP36*B*N     = 294912
// total 651648 floats = 2.6 MB

typedef _Float16 f16x4 __attribute__((ext_vector_type(4)));
typedef float f32x4 __attribute__((ext_vector_type(4)));

// raw hardware exp2 (v_exp_f32); CDNA interlocks handle the TRANS latency
__device__ __forceinline__ float exp2_hw(float x) {
  float r;
  __asm__ __volatile__("v_exp_f32 %0, %1" : "=v"(r) : "v"(x));
  return r;
}

__device__ __forceinline__ void decode_pair(int p36, int* pa, int* pd) {
  int a = 0, rem = p36;
  while (rem >= D - a) { rem -= (D - a); a++; }
  *pa = a; *pd = a + rem;
}

__device__ __forceinline__ float wave_reduce(float v) {
#pragma unroll
  for (int off = 32; off > 0; off >>= 1) v += __shfl_down(v, off);
  return v;
}

// compiler fence for wave-synchronous LDS phases (no runtime cost)
__device__ __forceinline__ void wsync() {
  __asm__ __volatile__("" ::: "memory");
  __builtin_amdgcn_wave_barrier();
  __asm__ __volatile__("" ::: "memory");
}

// Wave-synchronous Gauss-Jordan with partial pivoting on E x GJW system in
// LDS. ONE wave, zero block barriers; reads register-cached before writes
// each phase. On exit: M[r][E+c] = left^{-1} * right.
// Returns log|det(left)| (valid in every lane).
__device__ __forceinline__ float gj_wave(float (*M)[GJW], int lane) {
  float pivs[E];
#pragma unroll
  for (int k = 0; k < E; k++) {
    wsync();
    int pr = k;
    float best = fabsf(M[k][k]);
#pragma unroll
    for (int r = 1; r < E; r++) {
      if (r > k) {
        float v = fabsf(M[r][k]);
        if (v > best) { best = v; pr = r; }
      }
    }
    pivs[k] = M[pr][k];
    wsync();
    float tk = 0.f, pw = 0.f;
    if (lane < GJW) {
      float piv = M[pr][k];
      pw = M[pr][lane] / piv;
      tk = M[k][lane];
    }
    wsync();
    if (lane < GJW) {
      M[pr][lane] = tk;
      M[k][lane]  = pw;
    }
    wsync();
    float cf[4], pv[4], cur[4];
    int rr[4], cc[4];
#pragma unroll
    for (int t = 0; t < 4; t++) {
      int idx = lane + t * 64;
      if (idx < E * GJW) {
        int r = idx / GJW, c = idx - r * GJW;
        rr[t] = r; cc[t] = c;
        cf[t]  = M[r][k];
        pv[t]  = M[k][c];
        cur[t] = M[r][c];
      } else {
        rr[t] = k; cc[t] = 0; cf[t] = 0.f; pv[t] = 0.f; cur[t] = 0.f;
      }
    }
    wsync();
#pragma unroll
    for (int t = 0; t < 4; t++) {
      int idx = lane + t * 64;
      if (idx < E * GJW && rr[t] != k) {
        M[rr[t]][cc[t]] = fmaf(-cf[t], pv[t], cur[t]);
      }
    }
  }
  wsync();
  float ld = 0.f;
#pragma unroll
  for (int k = 0; k < E; k++) ld += logf(fabsf(pivs[k]));
  return ld;
}

// ---------------------------------------------------------------------------
// k_prep: ONE WAVE PER SYSTEM, 4 systems/block, no block barriers.
// S and Ainv are SYMMETRIC (S=(SigD+I)^-1 Sig = Sig(DSig+I)^-1), so only the
// 55-element upper triangle is hoisted to registers (off-diag pre-doubled) --
// the N-loop quadratic forms then need ZERO LDS reads. (R8's full-100-float
// hoist spilled; R9/R11's all-LDS version was a 120-cyc/load chain at 1
// wave/SIMD occupancy -> ~48us. This is the middle path.)
// waves (sid) [0, 576): pair systems -> W (log2e-scaled), CA, CB.
// waves [576, 704): A-path systems -> mu_delta[b,d], V[b,d,:].
__global__ __launch_bounds__(256) void k_prep(
    const float* __restrict__ obs_mean, const float* __restrict__ obs_var,
    const float* __restrict__ action_mean, const float* __restrict__ action_var,
    const float* __restrict__ cross_cov, const float* __restrict__ X,
    const float* __restrict__ ell, const float* __restrict__ alpha_sq,
    const float* __restrict__ beta, float* __restrict__ ws) {
  __shared__ float M[4][E][GJW];
  __shared__ float sSig[4][E * E];
  __shared__ float sMu[4][E], siLa[4][E], siLd[4][E];

  int tid = threadIdx.x;
  int wid = tid >> 6, lane = tid & 63;
  int sid = blockIdx.x * 4 + wid;

  if (sid >= NP36 * B) {
    // ===== A-path wave: mu_delta[b,d], V[b,d,:] =====
    int bd = sid - NP36 * B;
    int b = bd >> 3, d = bd & 7;
    if (lane < E) {
      sMu[wid][lane] = (lane < D) ? obs_mean[b * D + lane]
                                  : action_mean[b * FDIM + lane - D];
    }
    for (int idx = lane; idx < E * E; idx += 64) {
      int e = idx / E, f = idx % E;
      float v;
      if (e < D && f < D)      v = obs_var[(b * D + e) * D + f];
      else if (e < D)          v = cross_cov[(b * D + e) * FDIM + (f - D)];
      else if (f < D)          v = cross_cov[(b * D + f) * FDIM + (e - D)];
      else                     v = action_var[(b * FDIM + (e - D)) * FDIM + (f - D)];
      sSig[wid][idx] = v;
    }
    wsync();
    for (int idx = lane; idx < E * GJW; idx += 64) {
      int r = idx / GJW, c = idx % GJW;
      float v;
      if (c < E) {
        v = sSig[wid][r * E + c];
        if (r == c) { float l = ell[d * E + r]; v += l * l; }
      } else {
        v = (c - E == r) ? 1.0f : 0.0f;
      }
      M[wid][r][c] = v;
    }
    float lda = gj_wave(M[wid], lane);   // M[r][E+c] = Ainv (symmetric)
    // hoist Ainv upper triangle (off-diag doubled) -- 55 registers
    float At2[55];
#pragma unroll
    for (int e = 0; e < E; e++) {
#pragma unroll
      for (int f = e; f < E; f++) {
        float s = M[wid][e][E + f];
        At2[TRI(e, f)] = (e == f) ? s : (s + s);
      }
    }
    float a2 = alpha_sq[d];
    float logdetLam = 0.0f;
#pragma unroll
    for (int e = 0; e < E; e++) { float l = ell[d * E + e]; logdetLam += logf(l * l); }
    float c0 = 0.5f * (logdetLam - lda);
    float acc_mu = 0.0f, acc_w[E];
#pragma unroll
    for (int e = 0; e < E; e++) acc_w[e] = 0.0f;
#pragma unroll
    for (int t = 0; t < 8; t++) {
      int n = lane + t * 64;
      float x[E];
#pragma unroll
      for (int e = 0; e < E; e++) x[e] = X[n * E + e] - sMu[wid][e];
      float quad = 0.0f;
#pragma unroll
      for (int e = 0; e < E; e++) {
        float te = 0.0f;
#pragma unroll
        for (int f = e; f < E; f++) te = fmaf(At2[TRI(e, f)], x[f], te);
        quad = fmaf(x[e], te, quad);
      }
      float qval = a2 * __expf(c0 - 0.5f * quad);
      float bq = beta[d * N + n] * qval;
      acc_mu += bq;
#pragma unroll
      for (int e = 0; e < E; e++) acc_w[e] += bq * x[e];
    }
    acc_mu = wave_reduce(acc_mu);
#pragma unroll
    for (int e = 0; e < E; e++) acc_w[e] = wave_reduce(acc_w[e]);
    if (lane == 0) {
      ws[OFF_MUD + b * D + d] = acc_mu;
      float u[E];
#pragma unroll
      for (int f = 0; f < E; f++) {
        float s = 0.0f;
#pragma unroll
        for (int g = 0; g < E; g++) s += M[wid][f][E + g] * acc_w[g];
        u[f] = s;
      }
#pragma unroll
      for (int e = 0; e < E; e++) {
        float s = 0.0f;
#pragma unroll
        for (int f = 0; f < E; f++) s += sSig[wid][e * E + f] * u[f];
        ws[OFF_V + (b * D + d) * E + e] = s;
      }
    }
    return;
  }

  // ===== pair wave: W, CA, CB for (p36, b) =====
  int p36 = sid >> 4, b = sid & 15;
  int a, d;
  decode_pair(p36, &a, &d);
  int pb = p36 * B + b;
  if (lane < E) {
    sMu[wid][lane] = (lane < D) ? obs_mean[b * D + lane]
                                : action_mean[b * FDIM + lane - D];
    float la = ell[a * E + lane]; siLa[wid][lane] = 1.0f / (la * la);
    float ld = ell[d * E + lane]; siLd[wid][lane] = 1.0f / (ld * ld);
  }
  for (int idx = lane; idx < E * E; idx += 64) {
    int e = idx / E, f = idx % E;
    float v;
    if (e < D && f < D)      v = obs_var[(b * D + e) * D + f];
    else if (e < D)          v = cross_cov[(b * D + e) * FDIM + (f - D)];
    else if (f < D)          v = cross_cov[(b * D + f) * FDIM + (e - D)];
    else                     v = action_var[(b * FDIM + (e - D)) * FDIM + (f - D)];
    sSig[wid][idx] = v;
  }
  wsync();
  for (int idx = lane; idx < E * GJW; idx += 64) {
    int r = idx / GJW, c = idx % GJW;
    float v;
    if (c < E) v = sSig[wid][r * E + c] * (siLa[wid][c] + siLd[wid][c]) + ((r == c) ? 1.0f : 0.0f);
    else       v = sSig[wid][r * E + (c - E)];
    M[wid][r][c] = v;
  }
  float ldr = gj_wave(M[wid], lane);     // M[r][E+f] = S (symmetric)
  // hoist S upper triangle (off-diag doubled) -- 55 registers
  float St2[55];
#pragma unroll
  for (int e = 0; e < E; e++) {
#pragma unroll
    for (int f = e; f < E; f++) {
      float s = M[wid][e][E + f];
      St2[TRI(e, f)] = (e == f) ? s : (s + s);
    }
  }
  float lga = logf(alpha_sq[a]);
  float lgd = logf(alpha_sq[d]);
  for (int idx = lane; idx < E * E; idx += 64) {
    int e = idx / E, f = idx % E;
    ws[OFF_W + pb * (E * E) + idx] = LOG2E * M[wid][e][E + f] * siLa[wid][e] * siLd[wid][f];
  }
#pragma unroll
  for (int t = 0; t < 8; t++) {
    int n = lane + t * 64;
    float pa_[E], pd_[E];
    float s2a = 0.0f, s2b = 0.0f;
#pragma unroll
    for (int e = 0; e < E; e++) {
      float xe = X[n * E + e] - sMu[wid][e];
      pa_[e] = xe * siLa[wid][e];
      pd_[e] = xe * siLd[wid][e];
      s2a += xe * pa_[e];
      s2b += xe * pd_[e];
    }
    float da = 0.0f, db = 0.0f;
#pragma unroll
    for (int e = 0; e < E; e++) {
      float ta = 0.0f, td = 0.0f;
#pragma unroll
      for (int f = e; f < E; f++) {
        float s = St2[TRI(e, f)];
        ta = fmaf(s, pa_[f], ta);
        td = fmaf(s, pd_[f], td);
      }
      da = fmaf(pa_[e], ta, da);
      db = fmaf(pd_[e], td, db);
    }
    ws[OFF_CA + pb * N + n] = LOG2E * (lga - 0.5f * s2a + 0.5f * da - 0.5f * ldr);
    ws[OFF_CB + pb * N + n] = LOG2E * (lgd - 0.5f * s2b + 0.5f * db);
  }
}

// ---------------------------------------------------------------------------
// k_q: Q contraction per (pair, b, i-tile) via split-f16 MFMA (R11-proven:
// A-frag/sba register hoist, 54us, bank conflicts 0). NO launch_bounds
// override ((256,2) miscompiles to NaN -- R10/R12); NO dual-j ILP (R13:
// VGPR 104 dropped occupancy 27->17%, net -15%).
// Layouts (validated):
//   A frag: row = lane&15, k = 4*(lane>>4)+t   (T_aug rows)
//   B frag: col = lane&15, k = 4*(lane>>4)+t   (nu_aug rows)
//   C/D  : col = lane&15, row = 4*(lane>>4)+r
// K padding: kgrp==3 (k=12..15): B frags forced 0 (predicated); A frags may
// read finite spill (zero-padded array tail) -- product is 0 either way.
__global__ __launch_bounds__(256) void k_q(
    const float* __restrict__ obs_mean, const float* __restrict__ action_mean,
    const float* __restrict__ X, const float* __restrict__ beta,
    const float* __restrict__ invK, float* __restrict__ ws) {
  // stride-12-half rows (24 B): ds_read_b64 banks 6r+2kg mod 32 -> <=2-way (free)
  __shared__ __attribute__((aligned(16))) _Float16 snh[N * KA];        // nu_aug hi
  __shared__ __attribute__((aligned(16))) _Float16 snl[N * KA];        // nu_aug lo
  __shared__ __attribute__((aligned(16))) _Float16 sTh[TIL * KA + 8];  // T_aug hi (+zero pad)
  __shared__ __attribute__((aligned(16))) _Float16 sTl[TIL * KA + 8];  // T_aug lo
  __shared__ float sW[E * E];
  __shared__ float sMu[E];
  __shared__ __attribute__((aligned(16))) float sba[TIL];
  __shared__ float redw[8];

  int tid = threadIdx.x;
  int bx = blockIdx.x;
  int tile = bx & (NT - 1);
  int rest = bx >> 2;
  int b = rest & (B - 1);
  int p36 = rest >> 4;
  int a, d;
  decode_pair(p36, &a, &d);
  int pb = p36 * B + b;
  bool diag = (a == d);
  int i0 = tile * TIL;

  if (tid < E) sMu[tid] = (tid < D) ? obs_mean[b * D + tid] : action_mean[b * FDIM + tid - D];
  if (tid < E * E) sW[tid] = ws[OFF_W + pb * (E * E) + tid];
  if (tid < TIL) sba[tid] = beta[a * N + i0 + tid];
  if (tid < 8) { sTh[TIL * KA + tid] = (_Float16)0.f; sTl[TIL * KA + tid] = (_Float16)0.f; }
  __syncthreads();

  // build nu_aug hi/lo for all 512 j: [nu0..nu9, 1.0, cb_j]
  for (int jj = tid; jj < N; jj += 256) {
    float v[KA];
#pragma unroll
    for (int e = 0; e < E; e++) v[e] = X[jj * E + e] - sMu[e];
    v[10] = 1.0f;
    v[11] = ws[OFF_CB + (size_t)pb * N + jj];
#pragma unroll
    for (int k = 0; k < KA; k++) {
      _Float16 h = (_Float16)v[k];
      snh[jj * KA + k] = h;
      snl[jj * KA + k] = (_Float16)(v[k] - (float)h);
    }
  }

  // build T_aug hi/lo for this i-tile: [t0..t9, ca_i, 1.0]; 2 threads per row
  {
    int il = tid >> 1;
    int k0 = (tid & 1) * 6;
    float nu[E];
#pragma unroll
    for (int e = 0; e < E; e++) nu[e] = X[(i0 + il) * E + e] - sMu[e];
#pragma unroll
    for (int kk = 0; kk < 6; kk++) {
      int k = k0 + kk;
      float v;
      if (k < E) {
        v = 0.f;
#pragma unroll
        for (int e = 0; e < E; e++) v = fmaf(nu[e], sW[e * E + k], v);
      } else if (k == E) {
        v = ws[OFF_CA + (size_t)pb * N + i0 + il];
      } else {
        v = 1.0f;
      }
      _Float16 h = (_Float16)v;
      sTh[il * KA + k] = h;
      sTl[il * KA + k] = (_Float16)(v - (float)h);
    }
  }
  __syncthreads();

  // main loop: 4 waves x 8 j-tiles each; 8 i-tiles inner
  int lane = tid & 63;
  int w = tid >> 6;
  int c = lane & 15;
  int kg = lane >> 4;
  bool kval = (kg < 3);
  int koff = kg * 4;
  float accR = 0.f;
  float accT0 = 0.f, accT1 = 0.f, accT2 = 0.f, accT3 = 0.f;
  const float* invKa = invK + (size_t)a * N * N;
  const f32x4 zero4 = {0.f, 0.f, 0.f, 0.f};

  // hoist j-independent state into registers: 16 A-frags + 8 beta_a vectors
  f16x4 Ah[8], Al[8];
  f32x4 bav[8];
#pragma unroll
  for (int it = 0; it < 8; it++) {
    Ah[it] = *(const f16x4*)&sTh[(it * 16 + c) * KA + koff];
    Al[it] = *(const f16x4*)&sTl[(it * 16 + c) * KA + koff];
    bav[it] = *(const f32x4*)&sba[it * 16 + koff];
  }

  for (int jt8 = 0; jt8 < 8; jt8++) {
    int jt = (w << 3) + jt8;
    int j = (jt << 4) + c;
    f16x4 Bh = {(_Float16)0.f, (_Float16)0.f, (_Float16)0.f, (_Float16)0.f};
    f16x4 Bl = {(_Float16)0.f, (_Float16)0.f, (_Float16)0.f, (_Float16)0.f};
    if (kval) {
      Bh = *(const f16x4*)&snh[j * KA + koff];
      Bl = *(const f16x4*)&snl[j * KA + koff];
    }
    float bd = beta[d * N + j];
    const float* kvrow = invKa + (size_t)j * N + i0 + koff;
#pragma unroll
    for (int it = 0; it < 8; it++) {
      f32x4 m = __builtin_amdgcn_mfma_f32_16x16x16f16(Ah[it], Bh, zero4, 0, 0, 0);
      m = __builtin_amdgcn_mfma_f32_16x16x16f16(Ah[it], Bl, m, 0, 0, 0);
      m = __builtin_amdgcn_mfma_f32_16x16x16f16(Al[it], Bh, m, 0, 0, 0);
      float q0 = exp2_hw(m[0]);
      float q1 = exp2_hw(m[1]);
      float q2 = exp2_hw(m[2]);
      float q3 = exp2_hw(m[3]);
      float t = bav[it][0] * q0;
      t = fmaf(bav[it][1], q1, t);
      t = fmaf(bav[it][2], q2, t);
      t = fmaf(bav[it][3], q3, t);
      accR = fmaf(bd, t, accR);
      if (diag) {
        f32x4 r = *(const f32x4*)(kvrow + it * 16);
        accT0 = fmaf(r[0], q0, accT0);
        accT1 = fmaf(r[1], q1, accT1);
        accT2 = fmaf(r[2], q2, accT2);
        accT3 = fmaf(r[3], q3, accT3);
      }
    }
  }

  // reductions (wave shuffle + one LDS step)
  {
    float rr = wave_reduce(accR);
    int wid = tid >> 6, ln = tid & 63;
    if (ln == 0) redw[wid] = rr;
    if (diag) {
      float rt = wave_reduce((accT0 + accT1) + (accT2 + accT3));
      if (ln == 0) redw[4 + wid] = rt;
    }
    __syncthreads();
    if (tid == 0) {
      ws[OFF_EDDP + (p36 * B + b) * NT + tile] = redw[0] + redw[1] + redw[2] + redw[3];
      if (diag)
        ws[OFF_TRP + (a * B + b) * NT + tile] = redw[4] + redw[5] + redw[6] + redw[7];
    }
  }
}

// ---------------------------------------------------------------------------
// k_final: assembly (sums tile partials)
__global__ __launch_bounds__(64) void k_final(
    const float* __restrict__ obs_mean, const float* __restrict__ obs_var,
    const float* __restrict__ alpha_sq, const float* __restrict__ sigma_sq_eps,
    const float* __restrict__ ws, float* __restrict__ out) {
  int b = blockIdx.x;
  int tid = threadIdx.x;
  const float* mud = ws + OFF_MUD + b * D;
  if (tid < D) out[b * D + tid] = obs_mean[b * D + tid] + mud[tid];
  if (tid < D * D) {
    int i = tid / D, j = tid % D;
    int a = i < j ? i : j;
    int dd = i < j ? j : i;
    int p36 = a * D - a * (a - 1) / 2 + (dd - a);
    float edd = 0.0f;
#pragma unroll
    for (int tt = 0; tt < NT; tt++) edd += ws[OFF_EDDP + (p36 * B + b) * NT + tt];
    float sd = edd - mud[i] * mud[j];
    if (i == j) {
      float tr = 0.0f;
#pragma unroll
      for (int tt = 0; tt < NT; tt++) tr += ws[OFF_TRP + (i * B + b) * NT + tt];
      sd += alpha_sq[i] - tr + sigma_sq_eps[i];
    }
    const float* V = ws + OFF_V;
    float cxd = V[(b * D + j) * E + i];   // C_xd[b,i,j] = V[b,j,i]
    float cdx = V[(b * D + i) * E + j];   // C_xd[b,j,i] = V[b,i,j]
    out[B * D + b * D * D + tid] = obs_var[b * D * D + tid] + sd + cxd + cdx;
  }
}

// ---------------------------------------------------------------------------
extern "C" void kernel_launch(void* const* d_in, const int* in_sizes, int n_in,
                              void* d_out, int out_size, void* d_ws, size_t ws_size,
                              hipStream_t stream) {
  const float* obs_mean     = (const float*)d_in[0];
  const float* obs_var      = (const float*)d_in[1];
  const float* action_mean  = (const float*)d_in[2];
  const float* action_var   = (const float*)d_in[3];
  const float* cross_cov    = (const float*)d_in[4];
  const float* X_train      = (const float*)d_in[5];
  const float* ell          = (const float*)d_in[6];
  const float* alpha_sq     = (const float*)d_in[7];
  const float* sigma_sq_eps = (const float*)d_in[8];
  const float* beta         = (const float*)d_in[9];
  const float* inv_K        = (const float*)d_in[10];
  float* out = (float*)d_out;
  float* ws = (float*)d_ws;

  k_prep<<<NPREPB, 256, 0, stream>>>(obs_mean, obs_var, action_mean, action_var,
                                     cross_cov, X_train, ell, alpha_sq, beta, ws);
  k_q<<<NQ, 256, 0, stream>>>(obs_mean, action_mean, X_train, beta, inv_K, ws);
  k_final<<<B, 64, 0, stream>>>(obs_mean, obs_var, alpha_sq, sigma_sq_eps, ws, out);
}